// Round 15
// baseline (1986.661 us; speedup 1.0000x reference)
//
#include <hip/hip_runtime.h>

#define T4096 4096
#define CH 64
typedef unsigned long long u64;
typedef float v2f __attribute__((ext_vector_type(2)));

// ---------------------------------------------------------------------------
// QKV + fused L2-normalize, v2: 8x8 micro-tile (LDS-read-ratio fix).
// tile 128(s) x 64(c), K-step 64, 128 threads, grid 768 = exactly 3 blk/CU.
// Per k: 4 ds_read_b128 per 64 fma (1/16 ratio, was 1/8) -> LDS-pipe time
// halves to ~327 us = VALU floor. LDS [k][col^sw], sw = lk&28 == k&28 for
// all elements stored (lk 4-aligned). Scalar fma chains k-ascending ->
// bit-identical. Epilogue normalize butterfly for c = 8*txc + j:
// shfl_xor 4,2,1 (== offs 32,16,8 of the original 64-lane tree) then local
// j^4, j^2, j^1 -- same pairing tree, commutative-safe -> bit-exact
// (replica method HW-verified in R14). Q stored TILED [b][s/64][c/4][s%64][4]
// (v8 sim layout), normalized; K token-major normalized; V token-major raw.
// ---------------------------------------------------------------------------
__global__ __launch_bounds__(128) void gemm_qkv(
    const float* __restrict__ X,
    const float* __restrict__ Wq, const float* __restrict__ Wk, const float* __restrict__ Wv,
    float* __restrict__ QT, float* __restrict__ KT, float* __restrict__ VT)
{
    const float* W = (blockIdx.z == 0) ? Wq : (blockIdx.z == 1) ? Wk : Wv;
    const int b  = blockIdx.y;
    const int s0 = blockIdx.x * 128;

    __shared__ float As[64][132];   // [k][m^swz], m 0..127
    __shared__ float Bs[64][68];    // [k][c^swz], c 0..63

    const int tid = threadIdx.x;
    const int txc = tid & 7;   const int c0 = txc * 8;
    const int tym = tid >> 3;  const int m0 = tym * 8;   // 0..120
    const int lk  = (tid & 15) * 4;    // 0..60 (k-offset for staging)
    const int rA  = tid >> 4;          // 0..7  (row slot for staging)
    const int sw  = lk & 28;

    float acc[8][8];
#pragma unroll
    for (int i = 0; i < 8; ++i)
#pragma unroll
        for (int j = 0; j < 8; ++j) acc[i][j] = 0.f;

    const float* Xb = X + (size_t)b * CH * T4096;

    for (int k0 = 0; k0 < T4096; k0 += 64) {
#pragma unroll 4
        for (int p = 0; p < 16; ++p) {   // A: 128 rows x 64 k
            int row = rA + 8 * p;
            float4 v = *(const float4*)(W + (size_t)(s0 + row) * T4096 + k0 + lk);
            int col = row ^ sw;
            As[lk + 0][col] = v.x; As[lk + 1][col] = v.y;
            As[lk + 2][col] = v.z; As[lk + 3][col] = v.w;
        }
#pragma unroll 4
        for (int p = 0; p < 8; ++p) {    // B: 64 channel-rows x 64 k
            int row = rA + 8 * p;
            float4 v = *(const float4*)(Xb + (size_t)row * T4096 + k0 + lk);
            int col = row ^ sw;
            Bs[lk + 0][col] = v.x; Bs[lk + 1][col] = v.y;
            Bs[lk + 2][col] = v.z; Bs[lk + 3][col] = v.w;
        }
        __syncthreads();
#pragma unroll
        for (int k = 0; k < 64; ++k) {
            const int swk = k & 28;
            float4 a0 = *(const float4*)&As[k][(m0) ^ swk];
            float4 a1 = *(const float4*)&As[k][(m0 + 4) ^ swk];
            float4 b0 = *(const float4*)&Bs[k][(c0) ^ swk];
            float4 b1 = *(const float4*)&Bs[k][(c0 + 4) ^ swk];
            float am[8] = {a0.x,a0.y,a0.z,a0.w,a1.x,a1.y,a1.z,a1.w};
            float bn[8] = {b0.x,b0.y,b0.z,b0.w,b1.x,b1.y,b1.z,b1.w};
#pragma unroll
            for (int i = 0; i < 8; ++i)
#pragma unroll
                for (int j = 0; j < 8; ++j)
                    acc[i][j] = fmaf(am[i], bn[j], acc[i][j]);
        }
        __syncthreads();
    }

    if (blockIdx.z == 2) {
        // V: raw, token-major
#pragma unroll
        for (int i = 0; i < 8; ++i) {
            int s = s0 + m0 + i;
            float* dst = VT + ((size_t)b * T4096 + s) * CH + c0;
            *(float4*)(dst)     = make_float4(acc[i][0], acc[i][1], acc[i][2], acc[i][3]);
            *(float4*)(dst + 4) = make_float4(acc[i][4], acc[i][5], acc[i][6], acc[i][7]);
        }
        return;
    }

    // fused normalize: bit-exact replica of the 64-lane butterfly for
    // channel c = 8*txc + j (offs 32,16,8 -> shfl 4,2,1; offs 4,2,1 -> local)
#pragma unroll
    for (int i = 0; i < 8; ++i) {
        float p[8];
#pragma unroll
        for (int j = 0; j < 8; ++j) p[j] = acc[i][j] * acc[i][j];
#pragma unroll
        for (int j = 0; j < 8; ++j) p[j] += __shfl_xor(p[j], 4);
#pragma unroll
        for (int j = 0; j < 8; ++j) p[j] += __shfl_xor(p[j], 2);
#pragma unroll
        for (int j = 0; j < 8; ++j) p[j] += __shfl_xor(p[j], 1);
        float s4[8];
#pragma unroll
        for (int j = 0; j < 8; ++j) s4[j] = p[j] + p[j ^ 4];
        float s2[8];
#pragma unroll
        for (int j = 0; j < 8; ++j) s2[j] = s4[j] + s4[j ^ 2];
        float ss = s2[0] + s2[1];            // == s2[j] + s2[j^1] for all j
        float n  = fmaxf(sqrtf(ss), 1e-12f);

        int s = s0 + m0 + i;
        if (blockIdx.z == 0) {
            // Q: normalized, tiled [b][s/64][c4g][s%64][4]
            size_t t0q = (((size_t)b * 64 + (s >> 6)) * 16 + (c0 >> 2)) * 64 + (s & 63);
            *(float4*)(QT + t0q * 4) =
                make_float4(acc[i][0] / n, acc[i][1] / n, acc[i][2] / n, acc[i][3] / n);
            *(float4*)(QT + (t0q + 64) * 4) =
                make_float4(acc[i][4] / n, acc[i][5] / n, acc[i][6] / n, acc[i][7] / n);
        } else {
            // K: normalized, token-major
            float* dst = KT + ((size_t)b * T4096 + s) * CH + c0;
            *(float4*)(dst)     = make_float4(acc[i][0] / n, acc[i][1] / n, acc[i][2] / n, acc[i][3] / n);
            *(float4*)(dst + 4) = make_float4(acc[i][4] / n, acc[i][5] / n, acc[i][6] / n, acc[i][7] / n);
        }
    }
}

// ---------------------------------------------------------------------------
// Fused sim + top-9 (exact R10 v8): 2 rows x 8 cols per thread, 256-col
// chunks, tiled-Q loads (perfectly coalesced, half-wave broadcast).
// u64 keys + 32-bit pre-guard + shared row threshold. IDX bit-identical.
// ---------------------------------------------------------------------------
__global__ __launch_bounds__(512) void sim_topk(
    const float* __restrict__ Qr, const float* __restrict__ KT, int* __restrict__ IDX)
{
    const int wg = blockIdx.x;
    const int b  = wg & 7;              // XCD affinity
    const int t0 = (wg >> 3) * 32;

    __shared__ float Kn[32][68];

    const int tid = threadIdx.x;
    const int tx = tid & 31;
    const int ty = tid >> 5;            // 0..15

    {   // stage 32 rows x 64 floats (normalized K, token-major)
        int row = tid >> 4; int cc = (tid & 15) * 4;
        *(float4*)&Kn[row][cc] =
            *(const float4*)(KT + ((size_t)b * T4096 + t0 + row) * CH + cc);
    }
    __syncthreads();

    u64 tv[2][9];
#pragma unroll
    for (int r = 0; r < 2; ++r)
#pragma unroll
        for (int q = 0; q < 9; ++q) tv[r][q] = 0ULL;
    u64 thr[2] = {0ULL, 0ULL};
    unsigned thr_hi[2] = {0u, 0u};

    const float* qb0 = Qr + ((size_t)b * 64 * 1024 + tx) * 4;

    for (int it = 0; it < 16; ++it) {
        const float* bp = qb0 + (size_t)(it * 4) * 4096;
        float acc[2][8];
#pragma unroll
        for (int c = 0; c < 8; ++c) { acc[0][c] = 0.f; acc[1][c] = 0.f; }

#pragma unroll 1
        for (int c4g = 0; c4g < 16; ++c4g) {
            float4 qv[8];
#pragma unroll
            for (int cc = 0; cc < 8; ++cc)
                qv[cc] = *(const float4*)(bp + (size_t)(cc >> 1) * 4096
                                             + c4g * 256 + (cc & 1) * 128);
            float4 k0 = *(const float4*)&Kn[ty][c4g * 4];
            float4 k1 = *(const float4*)&Kn[16 + ty][c4g * 4];
#pragma unroll
            for (int cc = 0; cc < 8; ++cc) {
                acc[0][cc] = fmaf(k0.x, qv[cc].x, acc[0][cc]);
                acc[0][cc] = fmaf(k0.y, qv[cc].y, acc[0][cc]);
                acc[0][cc] = fmaf(k0.z, qv[cc].z, acc[0][cc]);
                acc[0][cc] = fmaf(k0.w, qv[cc].w, acc[0][cc]);
                acc[1][cc] = fmaf(k1.x, qv[cc].x, acc[1][cc]);
                acc[1][cc] = fmaf(k1.y, qv[cc].y, acc[1][cc]);
                acc[1][cc] = fmaf(k1.z, qv[cc].z, acc[1][cc]);
                acc[1][cc] = fmaf(k1.w, qv[cc].w, acc[1][cc]);
            }
        }

        bool ins = false;
        const int sb = it * 256 + tx;
#pragma unroll
        for (int rr = 0; rr < 2; ++rr)
#pragma unroll
            for (int cc = 0; cc < 8; ++cc) {
                float v = fmaxf(acc[rr][cc], 0.f);     // clip BEFORE top-k (as ref)
                unsigned vb = __float_as_uint(v);
                if (vb >= thr_hi[rr]) {                // cheap 32-bit pre-guard
                    int s = sb + 32 * cc;
                    u64 key = ((u64)vb << 32) | (u64)(4095 - s);
                    if (key > thr[rr]) {               // exact guard
                        u64 cv = key;
#pragma unroll
                        for (int p = 0; p < 9; ++p) {  // branchless sorted insert
                            u64 t  = tv[rr][p];
                            bool g = cv > t;
                            tv[rr][p] = g ? cv : t;
                            cv       = g ? t  : cv;
                        }
                        ins = true;
                    }
                }
            }
        if (__any(ins)) {   // refresh row lower bounds (max of lane 9ths)
#pragma unroll
            for (int r = 0; r < 2; ++r) {
                u64 m = tv[r][8];
#pragma unroll
                for (int msk = 1; msk < 32; msk <<= 1) {
                    u64 o = __shfl_xor(m, msk);
                    if (o > m) m = o;
                }
                thr[r] = m;
                thr_hi[r] = (unsigned)(m >> 32);
            }
        }
    }

    // in-wave merge: 32 col-lanes sharing ty hold partial 9-lists for row
    // rr*16+ty. 9 selection rounds of 32-lane xor-reduce on u64 keys.
#pragma unroll
    for (int rr = 0; rr < 2; ++rr) {
        u64 mv[9];
#pragma unroll
        for (int q = 0; q < 9; ++q) mv[q] = tv[rr][q];
        const int outrow = t0 + rr * 16 + ty;
        int* dst = IDX + ((size_t)b * T4096 + outrow) * 9;
        for (int sel = 0; sel < 9; ++sel) {
            u64 bk = mv[0]; int bl = tx;
#pragma unroll
            for (int m = 1; m < 32; m <<= 1) {
                u64 ok = __shfl_xor(bk, m);
                int ol = __shfl_xor(bl, m);
                if (ok > bk) { bk = ok; bl = ol; }
            }
            if (tx == 0) dst[sel] = 4095 - (int)(unsigned)(bk & 0xffffULL);
            if (tx == bl) {   // consume winner: static shift
#pragma unroll
                for (int q = 0; q < 8; ++q) mv[q] = mv[q + 1];
                mv[8] = 0ULL;
            }
        }
    }
}

// ---------------------------------------------------------------------------
// conv_w [o][i][j] -> wT3 [j][i/4][o][4] for coalesced float4 lane loads
// ---------------------------------------------------------------------------
__global__ void transpose_w(const float* __restrict__ cw, float* __restrict__ wT3)
{
    int idx = blockIdx.x * 256 + threadIdx.x;
    if (idx >= 64 * 64 * 9) return;
    int q   = idx & 3;
    int o   = (idx >> 2) & 63;
    int i4g = (idx >> 8) & 15;
    int j   = idx >> 12;
    wT3[idx] = cw[o * 576 + (i4g * 4 + q) * 9 + j];
}

// ---------------------------------------------------------------------------
// gather + conv1d(K=9, stride 9) + bias (exact R10/R14).
// ---------------------------------------------------------------------------
__global__ __launch_bounds__(256) void gather_conv(
    const float* __restrict__ VT, const int* __restrict__ IDX,
    const float* __restrict__ wT3, const float* __restrict__ conv_b,
    float* __restrict__ out1)
{
    const int b  = blockIdx.y;
    const int w  = threadIdx.x >> 6;
    const int o  = threadIdx.x & 63;
    const int t0 = (blockIdx.x * 4 + w) * 4;

    __shared__ float vv[4][4][9][64];
    __shared__ int   nb[4][36];

    if (o < 36) nb[w][o] = IDX[((size_t)b * T4096 + t0) * 9 + o];
    __syncthreads();

#pragma unroll
    for (int tok = 0; tok < 4; ++tok)
#pragma unroll
        for (int j = 0; j < 9; ++j) {
            int n = nb[w][tok * 9 + j];
            vv[w][tok][j][o] = VT[((size_t)b * T4096 + n) * CH + o];
        }
    __syncthreads();

    float cb = conv_b[o];
    float a0 = cb, a1 = cb, a2 = cb, a3 = cb;
    for (int j = 0; j < 9; ++j) {
#pragma unroll
        for (int i4 = 0; i4 < 16; ++i4) {
            float4 w4 = *(const float4*)(wT3 + (((size_t)j * 16 + i4) * 64 + o) * 4);
            float4 v0 = *(const float4*)&vv[w][0][j][i4 * 4];
            float4 v1 = *(const float4*)&vv[w][1][j][i4 * 4];
            float4 v2 = *(const float4*)&vv[w][2][j][i4 * 4];
            float4 v3 = *(const float4*)&vv[w][3][j][i4 * 4];
            a0 = fmaf(v0.x, w4.x, a0); a0 = fmaf(v0.y, w4.y, a0); a0 = fmaf(v0.z, w4.z, a0); a0 = fmaf(v0.w, w4.w, a0);
            a1 = fmaf(v1.x, w4.x, a1); a1 = fmaf(v1.y, w4.y, a1); a1 = fmaf(v1.z, w4.z, a1); a1 = fmaf(v1.w, w4.w, a1);
            a2 = fmaf(v2.x, w4.x, a2); a2 = fmaf(v2.y, w4.y, a2); a2 = fmaf(v2.z, w4.z, a2); a2 = fmaf(v2.w, w4.w, a2);
            a3 = fmaf(v3.x, w4.x, a3); a3 = fmaf(v3.y, w4.y, a3); a3 = fmaf(v3.z, w4.z, a3); a3 = fmaf(v3.w, w4.w, a3);
        }
    }
    out1[((size_t)b * T4096 + t0 + 0) * CH + o] = a0;
    out1[((size_t)b * T4096 + t0 + 1) * CH + o] = a1;
    out1[((size_t)b * T4096 + t0 + 2) * CH + o] = a2;
    out1[((size_t)b * T4096 + t0 + 3) * CH + o] = a3;
}

// ---------------------------------------------------------------------------
// Final GEMM (exact R14): tile 64x64, K-step 64, 256 thr, 4x4 micro packed.
// Per-output chain k-ascending -> bit-identical.
// ---------------------------------------------------------------------------
__global__ __launch_bounds__(256) void gemm_out(
    const float* __restrict__ out1, const float* __restrict__ Wo, float* __restrict__ Out)
{
    const int b  = blockIdx.y;
    const int s0 = blockIdx.x * 64;
    __shared__ float As[64][68];    // [k][c]
    __shared__ float Bs[64][68];    // [k][s^swz]
    const int tid = threadIdx.x;
    const int tx = tid & 15;  const int sl = tx * 4;
    const int my = tid >> 4;  const int c0 = my * 4;
    const int lk = (tid & 7) * 4;
    const int sw = lk;

    v2f acc2[4][2];
#pragma unroll
    for (int i = 0; i < 4; ++i) { acc2[i][0] = (v2f)0.f; acc2[i][1] = (v2f)0.f; }

    for (int k0 = 0; k0 < T4096; k0 += 64) {
        {   // A: out1 [t][c] -> [k][c]
            int r  = tid >> 2;
            int cL = (tid & 3) * 16;
            const float* src = out1 + ((size_t)b * T4096 + k0 + r) * CH + cL;
#pragma unroll
            for (int q = 0; q < 4; ++q)
                *(float4*)&As[r][cL + 4 * q] = *(const float4*)(src + 4 * q);
        }
#pragma unroll
        for (int kk = 0; kk < 2; ++kk) {
            const int kb = 32 * kk + lk;
#pragma unroll
            for (int p = 0; p < 2; ++p) {
                int row = (tid >> 3) + 32 * p;
                float4 v = *(const float4*)(Wo + (size_t)(s0 + row) * T4096 + k0 + kb);
                int col = row ^ sw;
                Bs[kb + 0][col] = v.x; Bs[kb + 1][col] = v.y;
                Bs[kb + 2][col] = v.z; Bs[kb + 3][col] = v.w;
            }
        }
        __syncthreads();
#pragma unroll
        for (int k = 0; k < 64; ++k) {
            const int swk = k & 28;
            float4 a  = *(const float4*)&As[k][c0];
            float4 bv = *(const float4*)&Bs[k][sl ^ swk];
            v2f b0 = {bv.x, bv.y};
            v2f b1 = {bv.z, bv.w};
            float av[4] = {a.x, a.y, a.z, a.w};
#pragma unroll
            for (int i = 0; i < 4; ++i) {
                v2f as = {av[i], av[i]};
                acc2[i][0] = __builtin_elementwise_fma(as, b0, acc2[i][0]);
                acc2[i][1] = __builtin_elementwise_fma(as, b1, acc2[i][1]);
            }
        }
        __syncthreads();
    }
#pragma unroll
    for (int i = 0; i < 4; ++i) {
        float* dst = Out + ((size_t)b * CH + c0 + i) * T4096 + s0 + sl;
        *(float4*)dst = make_float4(acc2[i][0].x, acc2[i][0].y, acc2[i][1].x, acc2[i][1].y);
    }
}

// ---------------------------------------------------------------------------
extern "C" void kernel_launch(void* const* d_in, const int* in_sizes, int n_in,
                              void* d_out, int out_size, void* d_ws, size_t ws_size,
                              hipStream_t stream)
{
    const float* x  = (const float*)d_in[0];
    const float* Wq = (const float*)d_in[1];
    const float* Wk = (const float*)d_in[2];
    const float* Wv = (const float*)d_in[3];
    const float* Wo = (const float*)d_in[4];
    const float* cw = (const float*)d_in[5];
    const float* cb = (const float*)d_in[6];
    float* Out = (float*)d_out;

    char* ws = (char*)d_ws;
    float* QT   = (float*)(ws);                               // 8 MB  Q tiled [b][blk][c4g][sl][4], normalized
    float* KT   = (float*)(ws + (size_t)8  * 1024 * 1024);    // 8 MB  [b][s][c], normalized
    float* VT   = (float*)(ws + (size_t)16 * 1024 * 1024);    // 8 MB  [b][s][c], raw
    int*   IDXb = (int*)  (ws + (size_t)24 * 1024 * 1024);    // 1.2 MB [b][t][9]
    float* wT3  = (float*)(ws + (size_t)26 * 1024 * 1024);    // 147 KB
    float* out1 = QT;   // QT dead after sim_topk; reuse as conv output [b][t][o]

    gemm_qkv<<<dim3(32, 8, 3), dim3(128), 0, stream>>>(x, Wq, Wk, Wv, QT, KT, VT);
    sim_topk<<<dim3(1024), dim3(512), 0, stream>>>(QT, KT, IDXb);
    transpose_w<<<dim3(144), dim3(256), 0, stream>>>(cw, wT3);
    gather_conv<<<dim3(256, 8), dim3(256), 0, stream>>>(VT, IDXb, wT3, cb, out1);
    gemm_out<<<dim3(64, 8), dim3(256), 0, stream>>>(out1, Wo, Out);
}

// Round 16
// 1650.004 us; speedup vs baseline: 1.2040x; 1.2040x over previous
//
#include <hip/hip_runtime.h>

#define T4096 4096
#define CH 64
typedef unsigned long long u64;
typedef float v2f __attribute__((ext_vector_type(2)));

// ---------------------------------------------------------------------------
// QKV + fused L2-normalize (R14 config, proven 695 us): tile 128(s) x 64(c),
// K-step 64, 512 thr, 4x4 micro (packed col-pairs). Scalar chains
// k-ascending -> bit-identical. Epilogue butterfly replica (R14-verified).
// Q stored 256-token-tiled channel-major: Qp[b][s/256][c][s%256]
// (fully-coalesced 16B-lane-stride loads in sim). K norm tok-major; V raw.
// ---------------------------------------------------------------------------
__global__ __launch_bounds__(512) void gemm_qkv(
    const float* __restrict__ X,
    const float* __restrict__ Wq, const float* __restrict__ Wk, const float* __restrict__ Wv,
    float* __restrict__ Qp, float* __restrict__ KT, float* __restrict__ VT)
{
    const float* W = (blockIdx.z == 0) ? Wq : (blockIdx.z == 1) ? Wk : Wv;
    const int b  = blockIdx.y;
    const int s0 = blockIdx.x * 128;

    __shared__ float As[64][132];   // [k][m^swz]
    __shared__ float Bs[64][68];    // [k][c^swz]

    const int tid = threadIdx.x;
    const int tx = tid & 15;   const int c0 = tx * 4;
    const int my = tid >> 4;   const int m0 = my * 4;   // 0..124
    const int lr = tid >> 3;            // 0..63
    const int lk = (tid & 7) * 4;       // 0..28
    const int sw = lk;

    v2f acc2[4][2];
#pragma unroll
    for (int i = 0; i < 4; ++i) { acc2[i][0] = (v2f)0.f; acc2[i][1] = (v2f)0.f; }

    const float* Xb = X + (size_t)b * CH * T4096;

    for (int k0 = 0; k0 < T4096; k0 += 64) {
#pragma unroll
        for (int kk = 0; kk < 2; ++kk) {
            const int kb = 32 * kk + lk;
#pragma unroll
            for (int p = 0; p < 2; ++p) {   // A: 128 rows
                int row = lr + 64 * p;
                float4 v = *(const float4*)(W + (size_t)(s0 + row) * T4096 + k0 + kb);
                int col = row ^ sw;
                As[kb + 0][col] = v.x; As[kb + 1][col] = v.y;
                As[kb + 2][col] = v.z; As[kb + 3][col] = v.w;
            }
            {   // B: 64 rows (channels)
                int row = lr;
                float4 v = *(const float4*)(Xb + (size_t)row * T4096 + k0 + kb);
                int col = row ^ sw;
                Bs[kb + 0][col] = v.x; Bs[kb + 1][col] = v.y;
                Bs[kb + 2][col] = v.z; Bs[kb + 3][col] = v.w;
            }
        }
        __syncthreads();
#pragma unroll
        for (int k = 0; k < 64; ++k) {
            const int swk = k & 28;
            float4 a  = *(const float4*)&As[k][m0 ^ swk];
            float4 bv = *(const float4*)&Bs[k][c0 ^ swk];
            v2f b0 = {bv.x, bv.y};
            v2f b1 = {bv.z, bv.w};
            float am[4] = {a.x, a.y, a.z, a.w};
#pragma unroll
            for (int i = 0; i < 4; ++i) {
                v2f as = {am[i], am[i]};
                acc2[i][0] = __builtin_elementwise_fma(as, b0, acc2[i][0]);
                acc2[i][1] = __builtin_elementwise_fma(as, b1, acc2[i][1]);
            }
        }
        __syncthreads();
    }

    if (blockIdx.z == 2) {
        // V: raw, token-major
#pragma unroll
        for (int i = 0; i < 4; ++i) {
            *(float4*)(VT + ((size_t)b * T4096 + s0 + m0 + i) * CH + c0) =
                make_float4(acc2[i][0].x, acc2[i][0].y, acc2[i][1].x, acc2[i][1].y);
        }
        return;
    }

    // fused normalize (bit-exact butterfly replica, R14-verified)
    float nrm[4];
#pragma unroll
    for (int i = 0; i < 4; ++i) {
        float p0 = acc2[i][0].x * acc2[i][0].x;
        float p1 = acc2[i][0].y * acc2[i][0].y;
        float p2 = acc2[i][1].x * acc2[i][1].x;
        float p3 = acc2[i][1].y * acc2[i][1].y;
        p0 += __shfl_xor(p0, 8); p1 += __shfl_xor(p1, 8);
        p2 += __shfl_xor(p2, 8); p3 += __shfl_xor(p3, 8);
        p0 += __shfl_xor(p0, 4); p1 += __shfl_xor(p1, 4);
        p2 += __shfl_xor(p2, 4); p3 += __shfl_xor(p3, 4);
        p0 += __shfl_xor(p0, 2); p1 += __shfl_xor(p1, 2);
        p2 += __shfl_xor(p2, 2); p3 += __shfl_xor(p3, 2);
        p0 += __shfl_xor(p0, 1); p1 += __shfl_xor(p1, 1);
        p2 += __shfl_xor(p2, 1); p3 += __shfl_xor(p3, 1);
        float r0 = p0 + p2;     // c^2 pairing
        float r1 = p1 + p3;
        float ss = r0 + r1;     // c^1 pairing
        nrm[i] = fmaxf(sqrtf(ss), 1e-12f);
    }

    if (blockIdx.z == 0) {
        // Q: normalized, Qp[b][s/256][c][s%256]; per j a float4 over tokens
        float vj[4][4];
#pragma unroll
        for (int i = 0; i < 4; ++i) {
            vj[0][i] = acc2[i][0].x / nrm[i];
            vj[1][i] = acc2[i][0].y / nrm[i];
            vj[2][i] = acc2[i][1].x / nrm[i];
            vj[3][i] = acc2[i][1].y / nrm[i];
        }
        int s = s0 + m0;        // 4 consecutive tokens, same 256-block
        size_t base = (((size_t)b * 16 + (s >> 8)) * 64);
#pragma unroll
        for (int j = 0; j < 4; ++j) {
            *(float4*)(Qp + (base + c0 + j) * 256 + (s & 255)) =
                make_float4(vj[j][0], vj[j][1], vj[j][2], vj[j][3]);
        }
    } else {
        // K: normalized, token-major
#pragma unroll
        for (int i = 0; i < 4; ++i) {
            *(float4*)(KT + ((size_t)b * T4096 + s0 + m0 + i) * CH + c0) =
                make_float4(acc2[i][0].x / nrm[i], acc2[i][0].y / nrm[i],
                            acc2[i][1].x / nrm[i], acc2[i][1].y / nrm[i]);
        }
    }
}

// ---------------------------------------------------------------------------
// Fused sim + top-9, v14: R14 structure (packed fma + chunk-max guard +
// v8 selection) with FULLY-COALESCED Q loads. Q layout [b][blk=s/256][c][sl].
// 1024 blocks x 512 thr; b = wg&7 (XCD), 32 rows/block.
// thread(tx=tid&31, ty=tid>>5): rows {ty,16+ty}; cols blk*256 + g*128 +
// tx*4 + {0..3}, g in {0,1} -> two 16B-lane-stride loads per channel
// (1 KB/wave-load, 100% line use; was 32B-stride half-wasted).
// Per (row,col) chain: scalar fma, c ascending 0..63, from 0.0f ->
// bit-identical sims; selection semantics == v8 -> IDX bit-identical.
// ---------------------------------------------------------------------------
__global__ __launch_bounds__(512) void sim_topk(
    const float* __restrict__ Qp, const float* __restrict__ KT, int* __restrict__ IDX)
{
    const int wg = blockIdx.x;
    const int b  = wg & 7;              // XCD affinity
    const int t0 = (wg >> 3) * 32;

    __shared__ float Kn[32][68];

    const int tid = threadIdx.x;
    const int tx = tid & 31;
    const int ty = tid >> 5;            // 0..15

    {   // stage 32 rows x 64 floats (normalized K, token-major)
        int row = tid >> 4; int cc = (tid & 15) * 4;
        *(float4*)&Kn[row][cc] =
            *(const float4*)(KT + ((size_t)b * T4096 + t0 + row) * CH + cc);
    }
    __syncthreads();

    u64 tv[2][9];
#pragma unroll
    for (int r = 0; r < 2; ++r)
#pragma unroll
        for (int q = 0; q < 9; ++q) tv[r][q] = 0ULL;
    u64 thr[2] = {0ULL, 0ULL};
    unsigned thr_hi[2] = {0u, 0u};

    const float* qb0 = Qp + (size_t)b * 16 * 64 * 256 + tx * 4;

    for (int blk = 0; blk < 16; ++blk) {
        const int cbase = blk * 256;
        const float* qk = qb0 + (size_t)blk * (64 * 256);

        v2f acc2[2][4];     // [row][pair]: pairs = (g0:0,1),(g0:2,3),(g1:0,1),(g1:2,3)
#pragma unroll
        for (int m = 0; m < 4; ++m) { acc2[0][m] = (v2f)0.f; acc2[1][m] = (v2f)0.f; }

#pragma unroll 2
        for (int c4g = 0; c4g < 16; ++c4g) {
            float4 kv0 = *(const float4*)&Kn[ty][c4g * 4];
            float4 kv1 = *(const float4*)&Kn[16 + ty][c4g * 4];
            float km0[4] = {kv0.x, kv0.y, kv0.z, kv0.w};
            float km1[4] = {kv1.x, kv1.y, kv1.z, kv1.w};
#pragma unroll
            for (int cs = 0; cs < 4; ++cs) {
                const float* qp = qk + (size_t)(c4g * 4 + cs) * 256;
                float4 qa = *(const float4*)(qp);          // cols tx*4+0..3
                float4 qb = *(const float4*)(qp + 128);    // cols 128+tx*4+0..3
                v2f q0 = {qa.x, qa.y};
                v2f q1 = {qa.z, qa.w};
                v2f q2 = {qb.x, qb.y};
                v2f q3 = {qb.z, qb.w};
                v2f k0 = {km0[cs], km0[cs]};
                v2f k1 = {km1[cs], km1[cs]};
                acc2[0][0] = __builtin_elementwise_fma(k0, q0, acc2[0][0]);
                acc2[0][1] = __builtin_elementwise_fma(k0, q1, acc2[0][1]);
                acc2[0][2] = __builtin_elementwise_fma(k0, q2, acc2[0][2]);
                acc2[0][3] = __builtin_elementwise_fma(k0, q3, acc2[0][3]);
                acc2[1][0] = __builtin_elementwise_fma(k1, q0, acc2[1][0]);
                acc2[1][1] = __builtin_elementwise_fma(k1, q1, acc2[1][1]);
                acc2[1][2] = __builtin_elementwise_fma(k1, q2, acc2[1][2]);
                acc2[1][3] = __builtin_elementwise_fma(k1, q3, acc2[1][3]);
            }
        }

        bool ins = false;
#pragma unroll
        for (int rr = 0; rr < 2; ++rr) {
            v2f m01 = __builtin_elementwise_max(acc2[rr][0], acc2[rr][1]);
            v2f m23 = __builtin_elementwise_max(acc2[rr][2], acc2[rr][3]);
            v2f mm  = __builtin_elementwise_max(m01, m23);
            float vmax = fmaxf(fmaxf(mm.x, mm.y), 0.f);
            // skip iff vmax < thr value (strict; ties enter) -> exact
            if (!(vmax < __uint_as_float(thr_hi[rr]))) {
#pragma unroll
                for (int m = 0; m < 4; ++m)
#pragma unroll
                    for (int h = 0; h < 2; ++h) {
                        float v = fmaxf(h ? acc2[rr][m].y : acc2[rr][m].x, 0.f);
                        unsigned vb = __float_as_uint(v);
                        if (vb >= thr_hi[rr]) {            // v8 pre-guard
                            int s = cbase + (m >> 1) * 128 + tx * 4 + (m & 1) * 2 + h;
                            u64 key = ((u64)vb << 32) | (u64)(4095 - s);
                            if (key > thr[rr]) {           // exact guard
                                u64 cv = key;
#pragma unroll
                                for (int p = 0; p < 9; ++p) {
                                    u64 t  = tv[rr][p];
                                    bool g = cv > t;
                                    tv[rr][p] = g ? cv : t;
                                    cv       = g ? t  : cv;
                                }
                                ins = true;
                            }
                        }
                    }
            }
        }
        if (__any(ins)) {   // refresh row lower bounds (max of lane 9ths)
#pragma unroll
            for (int r = 0; r < 2; ++r) {
                u64 m = tv[r][8];
#pragma unroll
                for (int msk = 1; msk < 32; msk <<= 1) {
                    u64 o = __shfl_xor(m, msk);
                    if (o > m) m = o;
                }
                thr[r] = m;
                thr_hi[r] = (unsigned)(m >> 32);
            }
        }
    }

    // in-wave merge: 32 col-lanes sharing ty hold partial 9-lists for row
    // rr*16+ty. 9 selection rounds of 32-lane xor-reduce on u64 keys.
#pragma unroll
    for (int rr = 0; rr < 2; ++rr) {
        u64 mv[9];
#pragma unroll
        for (int q = 0; q < 9; ++q) mv[q] = tv[rr][q];
        const int outrow = t0 + rr * 16 + ty;
        int* dst = IDX + ((size_t)b * T4096 + outrow) * 9;
        for (int sel = 0; sel < 9; ++sel) {
            u64 bk = mv[0]; int bl = tx;
#pragma unroll
            for (int m = 1; m < 32; m <<= 1) {
                u64 ok = __shfl_xor(bk, m);
                int ol = __shfl_xor(bl, m);
                if (ok > bk) { bk = ok; bl = ol; }
            }
            if (tx == 0) dst[sel] = 4095 - (int)(unsigned)(bk & 0xffffULL);
            if (tx == bl) {   // consume winner: static shift
#pragma unroll
                for (int q = 0; q < 8; ++q) mv[q] = mv[q + 1];
                mv[8] = 0ULL;
            }
        }
    }
}

// ---------------------------------------------------------------------------
// conv_w [o][i][j] -> wT3 [j][i/4][o][4] for coalesced float4 lane loads
// ---------------------------------------------------------------------------
__global__ void transpose_w(const float* __restrict__ cw, float* __restrict__ wT3)
{
    int idx = blockIdx.x * 256 + threadIdx.x;
    if (idx >= 64 * 64 * 9) return;
    int q   = idx & 3;
    int o   = (idx >> 2) & 63;
    int i4g = (idx >> 8) & 15;
    int j   = idx >> 12;
    wT3[idx] = cw[o * 576 + (i4g * 4 + q) * 9 + j];
}

// ---------------------------------------------------------------------------
// gather + conv1d(K=9, stride 9) + bias (exact R10/R14).
// ---------------------------------------------------------------------------
__global__ __launch_bounds__(256) void gather_conv(
    const float* __restrict__ VT, const int* __restrict__ IDX,
    const float* __restrict__ wT3, const float* __restrict__ conv_b,
    float* __restrict__ out1)
{
    const int b  = blockIdx.y;
    const int w  = threadIdx.x >> 6;
    const int o  = threadIdx.x & 63;
    const int t0 = (blockIdx.x * 4 + w) * 4;

    __shared__ float vv[4][4][9][64];
    __shared__ int   nb[4][36];

    if (o < 36) nb[w][o] = IDX[((size_t)b * T4096 + t0) * 9 + o];
    __syncthreads();

#pragma unroll
    for (int tok = 0; tok < 4; ++tok)
#pragma unroll
        for (int j = 0; j < 9; ++j) {
            int n = nb[w][tok * 9 + j];
            vv[w][tok][j][o] = VT[((size_t)b * T4096 + n) * CH + o];
        }
    __syncthreads();

    float cb = conv_b[o];
    float a0 = cb, a1 = cb, a2 = cb, a3 = cb;
    for (int j = 0; j < 9; ++j) {
#pragma unroll
        for (int i4 = 0; i4 < 16; ++i4) {
            float4 w4 = *(const float4*)(wT3 + (((size_t)j * 16 + i4) * 64 + o) * 4);
            float4 v0 = *(const float4*)&vv[w][0][j][i4 * 4];
            float4 v1 = *(const float4*)&vv[w][1][j][i4 * 4];
            float4 v2 = *(const float4*)&vv[w][2][j][i4 * 4];
            float4 v3 = *(const float4*)&vv[w][3][j][i4 * 4];
            a0 = fmaf(v0.x, w4.x, a0); a0 = fmaf(v0.y, w4.y, a0); a0 = fmaf(v0.z, w4.z, a0); a0 = fmaf(v0.w, w4.w, a0);
            a1 = fmaf(v1.x, w4.x, a1); a1 = fmaf(v1.y, w4.y, a1); a1 = fmaf(v1.z, w4.z, a1); a1 = fmaf(v1.w, w4.w, a1);
            a2 = fmaf(v2.x, w4.x, a2); a2 = fmaf(v2.y, w4.y, a2); a2 = fmaf(v2.z, w4.z, a2); a2 = fmaf(v2.w, w4.w, a2);
            a3 = fmaf(v3.x, w4.x, a3); a3 = fmaf(v3.y, w4.y, a3); a3 = fmaf(v3.z, w4.z, a3); a3 = fmaf(v3.w, w4.w, a3);
        }
    }
    out1[((size_t)b * T4096 + t0 + 0) * CH + o] = a0;
    out1[((size_t)b * T4096 + t0 + 1) * CH + o] = a1;
    out1[((size_t)b * T4096 + t0 + 2) * CH + o] = a2;
    out1[((size_t)b * T4096 + t0 + 3) * CH + o] = a3;
}

// ---------------------------------------------------------------------------
// Final GEMM (exact R14): tile 64x64, K-step 64, 256 thr, 4x4 micro packed.
// Per-output chain k-ascending -> bit-identical.
// ---------------------------------------------------------------------------
__global__ __launch_bounds__(256) void gemm_out(
    const float* __restrict__ out1, const float* __restrict__ Wo, float* __restrict__ Out)
{
    const int b  = blockIdx.y;
    const int s0 = blockIdx.x * 64;
    __shared__ float As[64][68];    // [k][c]
    __shared__ float Bs[64][68];    // [k][s^swz]
    const int tid = threadIdx.x;
    const int tx = tid & 15;  const int sl = tx * 4;
    const int my = tid >> 4;  const int c0 = my * 4;
    const int lk = (tid & 7) * 4;
    const int sw = lk;

    v2f acc2[4][2];
#pragma unroll
    for (int i = 0; i < 4; ++i) { acc2[i][0] = (v2f)0.f; acc2[i][1] = (v2f)0.f; }

    for (int k0 = 0; k0 < T4096; k0 += 64) {
        {   // A: out1 [t][c] -> [k][c]
            int r  = tid >> 2;
            int cL = (tid & 3) * 16;
            const float* src = out1 + ((size_t)b * T4096 + k0 + r) * CH + cL;
#pragma unroll
            for (int q = 0; q < 4; ++q)
                *(float4*)&As[r][cL + 4 * q] = *(const float4*)(src + 4 * q);
        }
#pragma unroll
        for (int kk = 0; kk < 2; ++kk) {
            const int kb = 32 * kk + lk;
#pragma unroll
            for (int p = 0; p < 2; ++p) {
                int row = (tid >> 3) + 32 * p;
                float4 v = *(const float4*)(Wo + (size_t)(s0 + row) * T4096 + k0 + kb);
                int col = row ^ sw;
                Bs[kb + 0][col] = v.x; Bs[kb + 1][col] = v.y;
                Bs[kb + 2][col] = v.z; Bs[kb + 3][col] = v.w;
            }
        }
        __syncthreads();
#pragma unroll
        for (int k = 0; k < 64; ++k) {
            const int swk = k & 28;
            float4 a  = *(const float4*)&As[k][c0];
            float4 bv = *(const float4*)&Bs[k][sl ^ swk];
            v2f b0 = {bv.x, bv.y};
            v2f b1 = {bv.z, bv.w};
            float av[4] = {a.x, a.y, a.z, a.w};
#pragma unroll
            for (int i = 0; i < 4; ++i) {
                v2f as = {av[i], av[i]};
                acc2[i][0] = __builtin_elementwise_fma(as, b0, acc2[i][0]);
                acc2[i][1] = __builtin_elementwise_fma(as, b1, acc2[i][1]);
            }
        }
        __syncthreads();
    }
#pragma unroll
    for (int i = 0; i < 4; ++i) {
        float* dst = Out + ((size_t)b * CH + c0 + i) * T4096 + s0 + sl;
        *(float4*)dst = make_float4(acc2[i][0].x, acc2[i][0].y, acc2[i][1].x, acc2[i][1].y);
    }
}

// ---------------------------------------------------------------------------
extern "C" void kernel_launch(void* const* d_in, const int* in_sizes, int n_in,
                              void* d_out, int out_size, void* d_ws, size_t ws_size,
                              hipStream_t stream)
{
    const float* x  = (const float*)d_in[0];
    const float* Wq = (const float*)d_in[1];
    const float* Wk = (const float*)d_in[2];
    const float* Wv = (const float*)d_in[3];
    const float* Wo = (const float*)d_in[4];
    const float* cw = (const float*)d_in[5];
    const float* cb = (const float*)d_in[6];
    float* Out = (float*)d_out;

    char* ws = (char*)d_ws;
    float* Qp   = (float*)(ws);                               // 8 MB  Q [b][s/256][c][s%256], normalized
    float* KT   = (float*)(ws + (size_t)8  * 1024 * 1024);    // 8 MB  [b][s][c], normalized
    float* VT   = (float*)(ws + (size_t)16 * 1024 * 1024);    // 8 MB  [b][s][c], raw
    int*   IDXb = (int*)  (ws + (size_t)24 * 1024 * 1024);    // 1.2 MB [b][t][9]
    float* wT3  = (float*)(ws + (size_t)26 * 1024 * 1024);    // 147 KB
    float* out1 = Qp;   // Qp dead after sim_topk; reuse as conv output [b][t][o]

    gemm_qkv<<<dim3(32, 8, 3), dim3(512), 0, stream>>>(x, Wq, Wk, Wv, Qp, KT, VT);
    sim_topk<<<dim3(1024), dim3(512), 0, stream>>>(Qp, KT, IDXb);
    transpose_w<<<dim3(144), dim3(256), 0, stream>>>(cw, wT3);
    gather_conv<<<dim3(256, 8), dim3(256), 0, stream>>>(VT, IDXb, wT3, cb, out1);
    gemm_out<<<dim3(64, 8), dim3(256), 0, stream>>>(out1, Wo, Out);
}

// Round 17
// 1583.141 us; speedup vs baseline: 1.2549x; 1.0422x over previous
//
#include <hip/hip_runtime.h>

#define T4096 4096
#define CH 64
typedef unsigned long long u64;
typedef float v2f __attribute__((ext_vector_type(2)));

// ---------------------------------------------------------------------------
// QKV + fused L2-normalize (exact R14, proven): tile 128(s) x 64(c),
// K-step 64, 512 thr, 4x4 micro (packed col-pairs). Scalar chains
// k-ascending -> bit-identical. Epilogue butterfly replica (R14-verified).
// Q stored CHANNEL-MAJOR QC[b][c][s]; K norm tok-major; V raw tok-major.
// ---------------------------------------------------------------------------
__global__ __launch_bounds__(512) void gemm_qkv(
    const float* __restrict__ X,
    const float* __restrict__ Wq, const float* __restrict__ Wk, const float* __restrict__ Wv,
    float* __restrict__ QC, float* __restrict__ KT, float* __restrict__ VT)
{
    const float* W = (blockIdx.z == 0) ? Wq : (blockIdx.z == 1) ? Wk : Wv;
    const int b  = blockIdx.y;
    const int s0 = blockIdx.x * 128;

    __shared__ float As[64][132];   // [k][m^swz]
    __shared__ float Bs[64][68];    // [k][c^swz]

    const int tid = threadIdx.x;
    const int tx = tid & 15;   const int c0 = tx * 4;
    const int my = tid >> 4;   const int m0 = my * 4;   // 0..124
    const int lr = tid >> 3;            // 0..63
    const int lk = (tid & 7) * 4;       // 0..28
    const int sw = lk;

    v2f acc2[4][2];
#pragma unroll
    for (int i = 0; i < 4; ++i) { acc2[i][0] = (v2f)0.f; acc2[i][1] = (v2f)0.f; }

    const float* Xb = X + (size_t)b * CH * T4096;

    for (int k0 = 0; k0 < T4096; k0 += 64) {
#pragma unroll
        for (int kk = 0; kk < 2; ++kk) {
            const int kb = 32 * kk + lk;
#pragma unroll
            for (int p = 0; p < 2; ++p) {   // A: 128 rows
                int row = lr + 64 * p;
                float4 v = *(const float4*)(W + (size_t)(s0 + row) * T4096 + k0 + kb);
                int col = row ^ sw;
                As[kb + 0][col] = v.x; As[kb + 1][col] = v.y;
                As[kb + 2][col] = v.z; As[kb + 3][col] = v.w;
            }
            {   // B: 64 rows (channels)
                int row = lr;
                float4 v = *(const float4*)(Xb + (size_t)row * T4096 + k0 + kb);
                int col = row ^ sw;
                Bs[kb + 0][col] = v.x; Bs[kb + 1][col] = v.y;
                Bs[kb + 2][col] = v.z; Bs[kb + 3][col] = v.w;
            }
        }
        __syncthreads();
#pragma unroll
        for (int k = 0; k < 64; ++k) {
            const int swk = k & 28;
            float4 a  = *(const float4*)&As[k][m0 ^ swk];
            float4 bv = *(const float4*)&Bs[k][c0 ^ swk];
            v2f b0 = {bv.x, bv.y};
            v2f b1 = {bv.z, bv.w};
            float am[4] = {a.x, a.y, a.z, a.w};
#pragma unroll
            for (int i = 0; i < 4; ++i) {
                v2f as = {am[i], am[i]};
                acc2[i][0] = __builtin_elementwise_fma(as, b0, acc2[i][0]);
                acc2[i][1] = __builtin_elementwise_fma(as, b1, acc2[i][1]);
            }
        }
        __syncthreads();
    }

    if (blockIdx.z == 2) {
        // V: raw, token-major
#pragma unroll
        for (int i = 0; i < 4; ++i) {
            *(float4*)(VT + ((size_t)b * T4096 + s0 + m0 + i) * CH + c0) =
                make_float4(acc2[i][0].x, acc2[i][0].y, acc2[i][1].x, acc2[i][1].y);
        }
        return;
    }

    // fused normalize (bit-exact butterfly replica)
    float nrm[4];
#pragma unroll
    for (int i = 0; i < 4; ++i) {
        float p0 = acc2[i][0].x * acc2[i][0].x;
        float p1 = acc2[i][0].y * acc2[i][0].y;
        float p2 = acc2[i][1].x * acc2[i][1].x;
        float p3 = acc2[i][1].y * acc2[i][1].y;
        p0 += __shfl_xor(p0, 8); p1 += __shfl_xor(p1, 8);
        p2 += __shfl_xor(p2, 8); p3 += __shfl_xor(p3, 8);
        p0 += __shfl_xor(p0, 4); p1 += __shfl_xor(p1, 4);
        p2 += __shfl_xor(p2, 4); p3 += __shfl_xor(p3, 4);
        p0 += __shfl_xor(p0, 2); p1 += __shfl_xor(p1, 2);
        p2 += __shfl_xor(p2, 2); p3 += __shfl_xor(p3, 2);
        p0 += __shfl_xor(p0, 1); p1 += __shfl_xor(p1, 1);
        p2 += __shfl_xor(p2, 1); p3 += __shfl_xor(p3, 1);
        float r0 = p0 + p2;     // c^2 pairing
        float r1 = p1 + p3;
        float ss = r0 + r1;     // c^1 pairing
        nrm[i] = fmaxf(sqrtf(ss), 1e-12f);
    }

    if (blockIdx.z == 0) {
        // Q: normalized, CHANNEL-major QC[b][c][s]; per j a float4 over tokens
        float vj[4][4];
#pragma unroll
        for (int i = 0; i < 4; ++i) {
            vj[0][i] = acc2[i][0].x / nrm[i];
            vj[1][i] = acc2[i][0].y / nrm[i];
            vj[2][i] = acc2[i][1].x / nrm[i];
            vj[3][i] = acc2[i][1].y / nrm[i];
        }
#pragma unroll
        for (int j = 0; j < 4; ++j) {
            *(float4*)(QC + ((size_t)b * CH + c0 + j) * T4096 + s0 + m0) =
                make_float4(vj[j][0], vj[j][1], vj[j][2], vj[j][3]);
        }
    } else {
        // K: normalized, token-major
#pragma unroll
        for (int i = 0; i < 4; ++i) {
            *(float4*)(KT + ((size_t)b * T4096 + s0 + m0 + i) * CH + c0) =
                make_float4(acc2[i][0].x / nrm[i], acc2[i][0].y / nrm[i],
                            acc2[i][1].x / nrm[i], acc2[i][1].y / nrm[i]);
        }
    }
}

// ---------------------------------------------------------------------------
// Fused sim + top-9 (R14 structure, HALVED BLOCK for occupancy):
// 2048 blocks x 256 thr = 8 blocks/CU x 4 waves = 32 waves/CU (HW cap).
// b = wg&7 (XCD affinity), 16 rows/block. thread(tx=tid&31, ty=tid>>5 in
// 0..7): rows {ty, 8+ty}, cols chk*256 + tx*8 + 0..7 (packed col-pairs
// from float4 halves of channel-major Q). Per-output scalar c-ascending
// fma chain -> sims bit-identical. Chunk-max pre-guard (strict <, exact),
// v8 per-candidate guard + insert, u64 keys, shared row thr via shfl_xor
// on __any(ins), v8 32-lane merge. IDX bit-identical.
// ---------------------------------------------------------------------------
__global__ __launch_bounds__(256) void sim_topk(
    const float* __restrict__ QC, const float* __restrict__ KT, int* __restrict__ IDX)
{
    const int wg = blockIdx.x;
    const int b  = wg & 7;              // XCD affinity
    const int t0 = (wg >> 3) * 16;

    __shared__ float Kn[16][68];

    const int tid = threadIdx.x;
    const int tx = tid & 31;
    const int ty = tid >> 5;            // 0..7

    {   // stage 16 rows x 64 floats (normalized K, token-major)
        int row = tid >> 4; int cc = (tid & 15) * 4;
        *(float4*)&Kn[row][cc] =
            *(const float4*)(KT + ((size_t)b * T4096 + t0 + row) * CH + cc);
    }
    __syncthreads();

    u64 tv[2][9];
#pragma unroll
    for (int r = 0; r < 2; ++r)
#pragma unroll
        for (int q = 0; q < 9; ++q) tv[r][q] = 0ULL;
    u64 thr[2] = {0ULL, 0ULL};
    unsigned thr_hi[2] = {0u, 0u};

    const float* qcb = QC + (size_t)b * CH * T4096 + tx * 8;

    for (int chk = 0; chk < 16; ++chk) {
        const int cbase = chk * 256;
        const float* qk = qcb + cbase;

        v2f acc2[2][4];
#pragma unroll
        for (int m = 0; m < 4; ++m) { acc2[0][m] = (v2f)0.f; acc2[1][m] = (v2f)0.f; }

#pragma unroll 2
        for (int c4g = 0; c4g < 16; ++c4g) {
            float4 kv0 = *(const float4*)&Kn[ty][c4g * 4];
            float4 kv1 = *(const float4*)&Kn[8 + ty][c4g * 4];
            float km0[4] = {kv0.x, kv0.y, kv0.z, kv0.w};
            float km1[4] = {kv1.x, kv1.y, kv1.z, kv1.w};
#pragma unroll
            for (int cs = 0; cs < 4; ++cs) {
                const float* qp = qk + (size_t)(c4g * 4 + cs) * T4096;
                float4 qa = *(const float4*)(qp);
                float4 qb = *(const float4*)(qp + 4);
                v2f q0 = {qa.x, qa.y};
                v2f q1 = {qa.z, qa.w};
                v2f q2 = {qb.x, qb.y};
                v2f q3 = {qb.z, qb.w};
                v2f k0 = {km0[cs], km0[cs]};
                v2f k1 = {km1[cs], km1[cs]};
                acc2[0][0] = __builtin_elementwise_fma(k0, q0, acc2[0][0]);
                acc2[0][1] = __builtin_elementwise_fma(k0, q1, acc2[0][1]);
                acc2[0][2] = __builtin_elementwise_fma(k0, q2, acc2[0][2]);
                acc2[0][3] = __builtin_elementwise_fma(k0, q3, acc2[0][3]);
                acc2[1][0] = __builtin_elementwise_fma(k1, q0, acc2[1][0]);
                acc2[1][1] = __builtin_elementwise_fma(k1, q1, acc2[1][1]);
                acc2[1][2] = __builtin_elementwise_fma(k1, q2, acc2[1][2]);
                acc2[1][3] = __builtin_elementwise_fma(k1, q3, acc2[1][3]);
            }
        }

        bool ins = false;
#pragma unroll
        for (int rr = 0; rr < 2; ++rr) {
            v2f m01 = __builtin_elementwise_max(acc2[rr][0], acc2[rr][1]);
            v2f m23 = __builtin_elementwise_max(acc2[rr][2], acc2[rr][3]);
            v2f mm  = __builtin_elementwise_max(m01, m23);
            float vmax = fmaxf(fmaxf(mm.x, mm.y), 0.f);
            // skip iff vmax < thr value (strict): no candidate can beat;
            // ties (==) still enter for index-order resolution. Exact.
            if (!(vmax < __uint_as_float(thr_hi[rr]))) {
#pragma unroll
                for (int m = 0; m < 4; ++m)
#pragma unroll
                    for (int h = 0; h < 2; ++h) {
                        float v = fmaxf(h ? acc2[rr][m].y : acc2[rr][m].x, 0.f);
                        unsigned vb = __float_as_uint(v);
                        if (vb >= thr_hi[rr]) {            // v8 pre-guard
                            int s = cbase + tx * 8 + 2 * m + h;
                            u64 key = ((u64)vb << 32) | (u64)(4095 - s);
                            if (key > thr[rr]) {           // exact guard
                                u64 cv = key;
#pragma unroll
                                for (int p = 0; p < 9; ++p) {
                                    u64 t  = tv[rr][p];
                                    bool g = cv > t;
                                    tv[rr][p] = g ? cv : t;
                                    cv       = g ? t  : cv;
                                }
                                ins = true;
                            }
                        }
                    }
            }
        }
        if (__any(ins)) {   // refresh row lower bounds (max of lane 9ths)
#pragma unroll
            for (int r = 0; r < 2; ++r) {
                u64 m = tv[r][8];
#pragma unroll
                for (int msk = 1; msk < 32; msk <<= 1) {
                    u64 o = __shfl_xor(m, msk);
                    if (o > m) m = o;
                }
                thr[r] = m;
                thr_hi[r] = (unsigned)(m >> 32);
            }
        }
    }

    // in-wave merge: 32 col-lanes sharing ty hold partial 9-lists for row
    // rr*8+ty. 9 selection rounds of 32-lane xor-reduce on u64 keys.
#pragma unroll
    for (int rr = 0; rr < 2; ++rr) {
        u64 mv[9];
#pragma unroll
        for (int q = 0; q < 9; ++q) mv[q] = tv[rr][q];
        const int outrow = t0 + rr * 8 + ty;
        int* dst = IDX + ((size_t)b * T4096 + outrow) * 9;
        for (int sel = 0; sel < 9; ++sel) {
            u64 bk = mv[0]; int bl = tx;
#pragma unroll
            for (int m = 1; m < 32; m <<= 1) {
                u64 ok = __shfl_xor(bk, m);
                int ol = __shfl_xor(bl, m);
                if (ok > bk) { bk = ok; bl = ol; }
            }
            if (tx == 0) dst[sel] = 4095 - (int)(unsigned)(bk & 0xffffULL);
            if (tx == bl) {   // consume winner: static shift
#pragma unroll
                for (int q = 0; q < 8; ++q) mv[q] = mv[q + 1];
                mv[8] = 0ULL;
            }
        }
    }
}

// ---------------------------------------------------------------------------
// conv_w [o][i][j] -> wT3 [j][i/4][o][4] for coalesced float4 lane loads
// ---------------------------------------------------------------------------
__global__ void transpose_w(const float* __restrict__ cw, float* __restrict__ wT3)
{
    int idx = blockIdx.x * 256 + threadIdx.x;
    if (idx >= 64 * 64 * 9) return;
    int q   = idx & 3;
    int o   = (idx >> 2) & 63;
    int i4g = (idx >> 8) & 15;
    int j   = idx >> 12;
    wT3[idx] = cw[o * 576 + (i4g * 4 + q) * 9 + j];
}

// ---------------------------------------------------------------------------
// gather + conv1d(K=9, stride 9) + bias (exact R10/R14).
// ---------------------------------------------------------------------------
__global__ __launch_bounds__(256) void gather_conv(
    const float* __restrict__ VT, const int* __restrict__ IDX,
    const float* __restrict__ wT3, const float* __restrict__ conv_b,
    float* __restrict__ out1)
{
    const int b  = blockIdx.y;
    const int w  = threadIdx.x >> 6;
    const int o  = threadIdx.x & 63;
    const int t0 = (blockIdx.x * 4 + w) * 4;

    __shared__ float vv[4][4][9][64];
    __shared__ int   nb[4][36];

    if (o < 36) nb[w][o] = IDX[((size_t)b * T4096 + t0) * 9 + o];
    __syncthreads();

#pragma unroll
    for (int tok = 0; tok < 4; ++tok)
#pragma unroll
        for (int j = 0; j < 9; ++j) {
            int n = nb[w][tok * 9 + j];
            vv[w][tok][j][o] = VT[((size_t)b * T4096 + n) * CH + o];
        }
    __syncthreads();

    float cb = conv_b[o];
    float a0 = cb, a1 = cb, a2 = cb, a3 = cb;
    for (int j = 0; j < 9; ++j) {
#pragma unroll
        for (int i4 = 0; i4 < 16; ++i4) {
            float4 w4 = *(const float4*)(wT3 + (((size_t)j * 16 + i4) * 64 + o) * 4);
            float4 v0 = *(const float4*)&vv[w][0][j][i4 * 4];
            float4 v1 = *(const float4*)&vv[w][1][j][i4 * 4];
            float4 v2 = *(const float4*)&vv[w][2][j][i4 * 4];
            float4 v3 = *(const float4*)&vv[w][3][j][i4 * 4];
            a0 = fmaf(v0.x, w4.x, a0); a0 = fmaf(v0.y, w4.y, a0); a0 = fmaf(v0.z, w4.z, a0); a0 = fmaf(v0.w, w4.w, a0);
            a1 = fmaf(v1.x, w4.x, a1); a1 = fmaf(v1.y, w4.y, a1); a1 = fmaf(v1.z, w4.z, a1); a1 = fmaf(v1.w, w4.w, a1);
            a2 = fmaf(v2.x, w4.x, a2); a2 = fmaf(v2.y, w4.y, a2); a2 = fmaf(v2.z, w4.z, a2); a2 = fmaf(v2.w, w4.w, a2);
            a3 = fmaf(v3.x, w4.x, a3); a3 = fmaf(v3.y, w4.y, a3); a3 = fmaf(v3.z, w4.z, a3); a3 = fmaf(v3.w, w4.w, a3);
        }
    }
    out1[((size_t)b * T4096 + t0 + 0) * CH + o] = a0;
    out1[((size_t)b * T4096 + t0 + 1) * CH + o] = a1;
    out1[((size_t)b * T4096 + t0 + 2) * CH + o] = a2;
    out1[((size_t)b * T4096 + t0 + 3) * CH + o] = a3;
}

// ---------------------------------------------------------------------------
// Final GEMM (exact R14): tile 64x64, K-step 64, 256 thr, 4x4 micro packed.
// Per-output chain k-ascending -> bit-identical.
// ---------------------------------------------------------------------------
__global__ __launch_bounds__(256) void gemm_out(
    const float* __restrict__ out1, const float* __restrict__ Wo, float* __restrict__ Out)
{
    const int b  = blockIdx.y;
    const int s0 = blockIdx.x * 64;
    __shared__ float As[64][68];    // [k][c]
    __shared__ float Bs[64][68];    // [k][s^swz]
    const int tid = threadIdx.x;
    const int tx = tid & 15;  const int sl = tx * 4;
    const int my = tid >> 4;  const int c0 = my * 4;
    const int lk = (tid & 7) * 4;
    const int sw = lk;

    v2f acc2[4][2];
#pragma unroll
    for (int i = 0; i < 4; ++i) { acc2[i][0] = (v2f)0.f; acc2[i][1] = (v2f)0.f; }

    for (int k0 = 0; k0 < T4096; k0 += 64) {
        {   // A: out1 [t][c] -> [k][c]
            int r  = tid >> 2;
            int cL = (tid & 3) * 16;
            const float* src = out1 + ((size_t)b * T4096 + k0 + r) * CH + cL;
#pragma unroll
            for (int q = 0; q < 4; ++q)
                *(float4*)&As[r][cL + 4 * q] = *(const float4*)(src + 4 * q);
        }
#pragma unroll
        for (int kk = 0; kk < 2; ++kk) {
            const int kb = 32 * kk + lk;
#pragma unroll
            for (int p = 0; p < 2; ++p) {
                int row = (tid >> 3) + 32 * p;
                float4 v = *(const float4*)(Wo + (size_t)(s0 + row) * T4096 + k0 + kb);
                int col = row ^ sw;
                Bs[kb + 0][col] = v.x; Bs[kb + 1][col] = v.y;
                Bs[kb + 2][col] = v.z; Bs[kb + 3][col] = v.w;
            }
        }
        __syncthreads();
#pragma unroll
        for (int k = 0; k < 64; ++k) {
            const int swk = k & 28;
            float4 a  = *(const float4*)&As[k][c0];
            float4 bv = *(const float4*)&Bs[k][sl ^ swk];
            v2f b0 = {bv.x, bv.y};
            v2f b1 = {bv.z, bv.w};
            float av[4] = {a.x, a.y, a.z, a.w};
#pragma unroll
            for (int i = 0; i < 4; ++i) {
                v2f as = {av[i], av[i]};
                acc2[i][0] = __builtin_elementwise_fma(as, b0, acc2[i][0]);
                acc2[i][1] = __builtin_elementwise_fma(as, b1, acc2[i][1]);
            }
        }
        __syncthreads();
    }
#pragma unroll
    for (int i = 0; i < 4; ++i) {
        float* dst = Out + ((size_t)b * CH + c0 + i) * T4096 + s0 + sl;
        *(float4*)dst = make_float4(acc2[i][0].x, acc2[i][0].y, acc2[i][1].x, acc2[i][1].y);
    }
}

// ---------------------------------------------------------------------------
extern "C" void kernel_launch(void* const* d_in, const int* in_sizes, int n_in,
                              void* d_out, int out_size, void* d_ws, size_t ws_size,
                              hipStream_t stream)
{
    const float* x  = (const float*)d_in[0];
    const float* Wq = (const float*)d_in[1];
    const float* Wk = (const float*)d_in[2];
    const float* Wv = (const float*)d_in[3];
    const float* Wo = (const float*)d_in[4];
    const float* cw = (const float*)d_in[5];
    const float* cb = (const float*)d_in[6];
    float* Out = (float*)d_out;

    char* ws = (char*)d_ws;
    float* QC   = (float*)(ws);                               // 8 MB  Q channel-major [b][c][s], normalized
    float* KT   = (float*)(ws + (size_t)8  * 1024 * 1024);    // 8 MB  [b][s][c], normalized
    float* VT   = (float*)(ws + (size_t)16 * 1024 * 1024);    // 8 MB  [b][s][c], raw
    int*   IDXb = (int*)  (ws + (size_t)24 * 1024 * 1024);    // 1.2 MB [b][t][9]
    float* wT3  = (float*)(ws + (size_t)26 * 1024 * 1024);    // 147 KB
    float* out1 = QC;   // QC dead after sim_topk; reuse as conv output [b][t][o]

    gemm_qkv<<<dim3(32, 8, 3), dim3(512), 0, stream>>>(x, Wq, Wk, Wv, QC, KT, VT);
    sim_topk<<<dim3(2048), dim3(256), 0, stream>>>(QC, KT, IDXb);
    transpose_w<<<dim3(144), dim3(256), 0, stream>>>(cw, wT3);
    gather_conv<<<dim3(256, 8), dim3(256), 0, stream>>>(VT, IDXb, wT3, cb, out1);
    gemm_out<<<dim3(64, 8), dim3(256), 0, stream>>>(out1, Wo, Out);
}